// Round 2
// baseline (3378.926 us; speedup 1.0000x reference)
//
#include <hip/hip_runtime.h>
#include <hip/hip_bf16.h>

typedef unsigned short u16;
typedef unsigned int u32;
typedef unsigned long long u64;
typedef __attribute__((ext_vector_type(8))) short short8;
typedef __attribute__((ext_vector_type(4))) float floatx4;

#define EPS 0.01f

// ---- workspace layout (bytes) --- total 630784 B ----
#define OFF_FLAGS  (0ull)         // int  [4][64]            1024 B
#define OFF_HPART  (4096ull)      // fp32 [2][4][16][64]     32768 B
#define OFF_HD     (40960ull)     // u32  [2][4][16][1024]   524288 B (lo16=h bf16, hi16=dh bf16)
#define OFF_XNORM  (565248ull)    // fp32 [16384]            65536 B

__device__ __forceinline__ u16 f2b(float v) {
  __hip_bfloat16 b = __float2bfloat16(v);
  return *reinterpret_cast<u16*>(&b);
}
__device__ __forceinline__ float b2f(u16 u) {
  u32 x = ((u32)u) << 16;
  return __uint_as_float(x);
}
__device__ __forceinline__ float halfsel(float w, int hi) {
  u32 u = __float_as_uint(w);
  return b2f((u16)(hi ? (u >> 16) : (u & 0xffffu)));
}
__device__ __forceinline__ float sigm(float x) { return 1.0f / (1.0f + __expf(-x)); }
__device__ __forceinline__ float tanh_(float x) { return 2.0f / (1.0f + __expf(-2.0f * x)) - 1.0f; }

// system-scope coherent 8B load, order-pinned by volatile asm. Used where we
// need a BATCH of loads all in flight simultaneously: plain __hip_atomic_load
// gets sunk to its use by the RP-driven scheduler (round-1 post-mortem:
// VGPR=84 proved batching never happened -> distance-0 pipeline, 8 exposed
// latencies/step). The asm pins issue order and forces all dests live.
#define LD_SYS_ASM(dst, ptr) \
  asm volatile("global_load_dwordx2 %0, %1, off sc0 sc1" : "=v"(dst) : "v"(ptr))

__device__ __forceinline__ u64 ld_sys_u64(const u64* p) {
  return __hip_atomic_load(p, __ATOMIC_RELAXED, __HIP_MEMORY_SCOPE_SYSTEM);
}

// prex chunk addressing (unchanged): pre-activation for (m = t*64+b,
// col = q*1024 + jt*16 + jj) lives as bf16 inside d_out at fp32 word
// (q>=2 ? 16777216 : 0) + m*1024 + jt*16 + (q&1)*8 + (jj>>1), half = jj&1.

// ---------------- xnorm2[t*64+b] = sum_k x[t,b,k]^2 ----------------
__global__ void xnorm_kernel(const float* __restrict__ x, float* __restrict__ xn) {
  const int wid = threadIdx.x >> 6, lane = threadIdx.x & 63;
  const int row = blockIdx.x * 4 + wid;
  const float4* p = (const float4*)(x + (size_t)row * 1024);
  float s = 0.f;
  #pragma unroll
  for (int i = 0; i < 4; ++i) {
    float4 v = p[lane + i * 64];
    s += v.x * v.x + v.y * v.y + v.z * v.z + v.w * v.w;
  }
  for (int o = 32; o; o >>= 1) s += __shfl_down(s, o);
  if (lane == 0) xn[row] = s;
}

// ------- prex = x @ W_ih^T + (b_ih+b_hh), fp32 in, bf16 chunks into d_out -------
#define LDA 88
__global__ __launch_bounds__(256) void pregemm_kernel(const float* __restrict__ A,
                                                      const float* __restrict__ Bw,
                                                      const float* __restrict__ bih,
                                                      const float* __restrict__ bhh,
                                                      u16* __restrict__ O) {
  __shared__ u16 Al[128 * LDA];
  __shared__ u16 Bl[128 * LDA];
  const int tid = threadIdx.x, lane = tid & 63, wid = tid >> 6;
  const int bm = blockIdx.x & 127, bn = blockIdx.x >> 7;
  const size_t m0 = (size_t)bm * 128, n0 = (size_t)bn * 128;
  const int wrow = (wid & 1) * 64, wcol = (wid >> 1) * 64;
  const int lrow = lane & 15, lko = (lane >> 4) * 8;
  floatx4 acc[4][4];
  #pragma unroll
  for (int i = 0; i < 4; ++i)
    #pragma unroll
    for (int j = 0; j < 4; ++j) acc[i][j] = (floatx4)(0.0f);

  for (int k0 = 0; k0 < 1024; k0 += 64) {
    __syncthreads();
    #pragma unroll
    for (int i = 0; i < 8; ++i) {
      int cid = tid + i * 256;
      int row = cid >> 4;
      int kc = cid & 15;
      float4 va = *(const float4*)&A[(m0 + row) * 1024 + k0 + kc * 4];
      ushort4 oa;
      oa.x = f2b(va.x); oa.y = f2b(va.y); oa.z = f2b(va.z); oa.w = f2b(va.w);
      *(ushort4*)&Al[row * LDA + kc * 4] = oa;
      float4 vb = *(const float4*)&Bw[(n0 + row) * 1024 + k0 + kc * 4];
      ushort4 ob;
      ob.x = f2b(vb.x); ob.y = f2b(vb.y); ob.z = f2b(vb.z); ob.w = f2b(vb.w);
      *(ushort4*)&Bl[row * LDA + kc * 4] = ob;
    }
    __syncthreads();
    #pragma unroll
    for (int ks = 0; ks < 2; ++ks) {
      short8 af[4], bf[4];
      #pragma unroll
      for (int i = 0; i < 4; ++i)
        af[i] = *(const short8*)&Al[(wrow + i * 16 + lrow) * LDA + ks * 32 + lko];
      #pragma unroll
      for (int j = 0; j < 4; ++j)
        bf[j] = *(const short8*)&Bl[(wcol + j * 16 + lrow) * LDA + ks * 32 + lko];
      #pragma unroll
      for (int i = 0; i < 4; ++i)
        #pragma unroll
        for (int j = 0; j < 4; ++j)
          acc[i][j] = __builtin_amdgcn_mfma_f32_16x16x32_bf16(af[i], bf[j], acc[i][j], 0, 0, 0);
    }
  }
  #pragma unroll
  for (int j = 0; j < 4; ++j) {
    const size_t col = n0 + wcol + j * 16 + lrow;
    const float bv = bih[col] + bhh[col];
    const size_t q = col >> 10;
    const size_t jt = (col & 1023) >> 4;
    const size_t jj = col & 15;
    const size_t cbase = ((q >= 2) ? 33554432ull : 0ull) + jt * 32 + (q & 1) * 16 + jj;
    #pragma unroll
    for (int i = 0; i < 4; ++i) {
      const size_t rowb = m0 + wrow + i * 16 + (lane >> 4) * 4;
      #pragma unroll
      for (int r = 0; r < 4; ++r) O[cbase + (rowb + r) * 2048] = f2b(acc[i][j][r] + bv);
    }
  }
}

// ---------------- persistent recurrent kernel v4 ----------------
// v3 post-mortem: VGPR=84 proved the "batched" A-loads were sunk back to
// distance-0 by the RP scheduler -> regression. v4 pins the batch in inline
// asm: 32 A-fragment + 2 hpart global_load_dwordx2 (sc0 sc1) issued
// back-to-back, one s_waitcnt vmcnt(0) + sched_barrier(0), then pure
// register/LDS GEMM. One pipelined system-scope latency instead of eight.
// Keeps v3's per-wave flag poll, deferred hn consumption, 2 barriers/step.
__global__ __launch_bounds__(256, 1) void recurrent_kernel(
    const float* __restrict__ gin, const float* __restrict__ whh,
    const float* __restrict__ xnorm2, u32* hd, float* hpart, int* flags, float* out) {
  extern __shared__ char smem[];
  u16* Wlds = (u16*)smem;                   // [64][1032]  132096 B
  float* rbuf = (float*)(smem + 132096);    // [2][4][4][3][64] fp32 = 24576 B

  const int tid = threadIdx.x, lane = tid & 63, wid = tid >> 6;
  const int grp = blockIdx.x & 3, jt = blockIdx.x >> 2;
  const int lrow = lane & 15, hv = lane >> 4, lko = hv * 8;
  const int j = jt * 16 + lrow;     // this lane's output column
  const int bloc = hv * 4 + wid;    // this lane's local batch row (0..15)
  const int pj = wid * 16 + lrow;   // producer jt this lane polls (wave's K quarter)

  // W_hh slice: LDS row q*16+jj <- global row q*1024 + jt*16 + jj (fp32 -> bf16)
  #pragma unroll
  for (int it = 0; it < 64; ++it) {
    int cid = tid + it * 256;
    int rowl = cid >> 8;
    int kc = cid & 255;
    int q = rowl >> 4, jj = rowl & 15;
    size_t grow = (size_t)q * 1024 + (size_t)jt * 16 + jj;
    float4 v = *(const float4*)&whh[grow * 1024 + kc * 4];
    ushort4 o;
    o.x = f2b(v.x); o.y = f2b(v.y); o.z = f2b(v.z); o.w = f2b(v.w);
    *(ushort4*)&Wlds[rowl * 1032 + kc * 4] = o;
  }
  __syncthreads();

  float cr = 0.f, dcr = 0.f;

  for (int t = 0; t < 256; ++t) {
    const int p = t & 1, p2 = p ^ 1;
    const size_t m = (size_t)t * 64 + grp * 16 + bloc;

    // ---- prefetch (producer-independent data) BEFORE the poll ----
    float gv[4];
    #pragma unroll
    for (int q = 0; q < 4; ++q) gv[q] = EPS * gin[m * 4096 + (size_t)q * 1024 + j];
    const size_t fb = m * 1024 + (size_t)jt * 16 + (lrow >> 1);
    float pw0 = out[fb];
    float pw1 = out[fb + 8];
    float pw2 = out[16777216ull + fb];
    float pw3 = out[16777216ull + fb + 8];
    float xnv = xnorm2[m];
    asm volatile("" ::: "memory");  // pin prefetch issue before the poll

    floatx4 acc[2][4];
    #pragma unroll
    for (int m2 = 0; m2 < 2; ++m2)
      #pragma unroll
      for (int q = 0; q < 4; ++q) acc[m2][q] = (floatx4)(0.0f);

    u64 q0v = 0, q1v = 0;  // hpart quads (loaded in the batch, consumed post-barrier)

    if (t > 0) {
      // ---- per-wave poll: only this wave's 16 producers (own jt exempt) ----
      for (int it = 0; it < 4000000; ++it) {
        int v = __hip_atomic_load(&flags[grp * 64 + pj], __ATOMIC_RELAXED,
                                  __HIP_MEMORY_SCOPE_SYSTEM);
        if (pj == jt) v = 0x7fffffff;
        if (__all(v >= t)) break;
        __builtin_amdgcn_s_sleep(1);
      }
      asm volatile("" ::: "memory");

      // ---- issue ALL loads of the step back-to-back (asm-pinned batch):
      //      32 x A-fragment u64 + 2 x hpart u64. One vmcnt(0) drain. ----
      const u32* hdrow = hd + ((size_t)(p * 4 + grp)) * 16384 + (size_t)lrow * 1024;
      u64 Abuf[32];
      #pragma unroll
      for (int ks = 0; ks < 8; ++ks) {
        const int kb = wid * 256 + ks * 32 + lko;
        #pragma unroll
        for (int i = 0; i < 4; ++i) {
          const u64* ap = (const u64*)(hdrow + kb + 2 * i);
          LD_SYS_ASM(Abuf[4 * ks + i], ap);
        }
      }
      const u64* hp = (const u64*)(hpart + ((size_t)(p * 4 + grp) * 16 + bloc) * 64 + lrow * 4);
      LD_SYS_ASM(q0v, hp);
      LD_SYS_ASM(q1v, hp + 1);
      asm volatile("s_waitcnt vmcnt(0)" ::: "memory");
      __builtin_amdgcn_sched_barrier(0);  // rule #18: keep unpack below the wait

      // ---- GEMM: wave wid owns K quarter [wid*256, wid*256+256) ----
      #pragma unroll
      for (int ks = 0; ks < 8; ++ks) {
        short8 a0, a1;
        #pragma unroll
        for (int i = 0; i < 4; ++i) {
          u32 lo = (u32)Abuf[4 * ks + i];
          u32 hi2 = (u32)(Abuf[4 * ks + i] >> 32);
          // a0 word i = lo16(w[2i]) | lo16(w[2i+1])<<16 ; a1 = hi16 halves
          ((u32*)&a0)[i] = __builtin_amdgcn_perm(hi2, lo, 0x05040100u);
          ((u32*)&a1)[i] = __builtin_amdgcn_perm(hi2, lo, 0x07060302u);
        }
        const int k0 = wid * 256 + ks * 32;
        #pragma unroll
        for (int q = 0; q < 4; ++q) {
          short8 bq = *(const short8*)&Wlds[(q * 16 + lrow) * 1032 + k0 + lko];
          acc[0][q] = __builtin_amdgcn_mfma_f32_16x16x32_bf16(a0, bq, acc[0][q], 0, 0, 0);
          acc[1][q] = __builtin_amdgcn_mfma_f32_16x16x32_bf16(a1, bq, acc[1][q], 0, 0, 0);
        }
      }
    }

    // ---- cross-wave K reduction: wave w keeps element r=w, exchanges the rest ----
    float fin[2][4] = {{0.f, 0.f, 0.f, 0.f}, {0.f, 0.f, 0.f, 0.f}};
    float hn = 0.f;
    if (t > 0) {
      // rbuf WAR vs step t-1 reads is covered by the end-of-step barrier
      #pragma unroll
      for (int m2 = 0; m2 < 2; ++m2)
        #pragma unroll
        for (int q = 0; q < 4; ++q)
          #pragma unroll
          for (int s2 = 0; s2 < 3; ++s2) {
            int r = s2 + (s2 >= wid ? 1 : 0);
            rbuf[((((m2 * 4 + q) * 4 + wid) * 3 + s2) << 6) + lane] = acc[m2][q][r];
          }
      __syncthreads();
      #pragma unroll
      for (int m2 = 0; m2 < 2; ++m2)
        #pragma unroll
        for (int q = 0; q < 4; ++q) {
          float sfin = acc[m2][q][wid];
          #pragma unroll
          for (int w2 = 0; w2 < 4; ++w2)
            if (w2 != wid) {
              int slot = wid - (wid > w2 ? 1 : 0);
              sfin += rbuf[((((m2 * 4 + q) * 4 + w2) * 3 + slot) << 6) + lane];
            }
          fin[m2][q] = sfin;
        }
      // ---- |h|^2: data already in q0v/q1v from the batch ----
      float s = __uint_as_float((u32)q0v) + __uint_as_float((u32)(q0v >> 32)) +
                __uint_as_float((u32)q1v) + __uint_as_float((u32)(q1v >> 32));
      s += __shfl_xor(s, 1);
      s += __shfl_xor(s, 2);
      s += __shfl_xor(s, 4);
      s += __shfl_xor(s, 8);
      hn = s;
    }

    // ---- epilogue: one cell (bloc, j) per lane ----
    {
      const int hi = lrow & 1;
      float pre0 = halfsel(pw0, hi), pre1 = halfsel(pw1, hi);
      float pre2 = halfsel(pw2, hi), pre3 = halfsel(pw3, hi);
      float sum2 = xnv + hn;
      float nrm = sqrtf(sum2 + 2.0f);
      float inv = 1.0f / nrm;
      float s_ = sum2 * inv;
      float pv0 = fin[0][0] + pre0, pv1 = fin[0][1] + pre1;
      float pv2 = fin[0][2] + pre2, pv3 = fin[0][3] + pre3;
      float d0 = gv[0] * (s_ + inv) + gv[1] * inv + fin[1][0];
      float d1 = gv[1] * s_ + (gv[2] + gv[3]) * inv + fin[1][1];
      float d2 = gv[2] * s_ + (gv[0] + gv[1]) * inv + fin[1][2];
      float d3 = gv[3] * s_ + (gv[2] + gv[3]) * inv + fin[1][3];
      float iv = sigm(pv0), fv = sigm(pv1), gg = tanh_(pv2), ov = sigm(pv3);
      float di = iv * (1.f - iv) * d0;
      float df = fv * (1.f - fv) * d1;
      float dgg = (1.f - gg * gg) * d2;
      float dov = ov * (1.f - ov) * d3;
      float c2 = fv * cr + iv * gg;
      float dc2 = df * cr + fv * dcr + di * gg + iv * dgg;
      float tc = tanh_(c2);
      float h2 = ov * tc;
      float dh2 = dov * tc + ov * (1.f - tc * tc) * dc2;
      cr = c2;
      dcr = dc2;
      out[m * 1024 + j] = h2;
      out[16777216ull + m * 1024 + j] = dh2;
      u32 packv = (u32)f2b(h2) | ((u32)f2b(dh2) << 16);
      __hip_atomic_store(&hd[((size_t)(p2 * 4 + grp)) * 16384 + (size_t)bloc * 1024 + j],
                         packv, __ATOMIC_RELAXED, __HIP_MEMORY_SCOPE_SYSTEM);
      float v2 = h2 * h2;
      v2 += __shfl_xor(v2, 1);
      v2 += __shfl_xor(v2, 2);
      v2 += __shfl_xor(v2, 4);
      v2 += __shfl_xor(v2, 8);
      if (lrow == 0)
        __hip_atomic_store(&hpart[((size_t)(p2 * 4 + grp) * 16 + bloc) * 64 + jt],
                           v2, __ATOMIC_RELAXED, __HIP_MEMORY_SCOPE_SYSTEM);
    }
    __syncthreads();  // drains vmcnt for ALL waves' state stores before flag
    if (tid == 0)
      __hip_atomic_store(&flags[grp * 64 + jt], t + 1, __ATOMIC_RELAXED,
                         __HIP_MEMORY_SCOPE_SYSTEM);
  }
}

extern "C" void kernel_launch(void* const* d_in, const int* in_sizes, int n_in,
                              void* d_out, int out_size, void* d_ws, size_t ws_size,
                              hipStream_t stream) {
  const float* x = (const float*)d_in[0];
  const float* g = (const float*)d_in[1];
  const float* wih = (const float*)d_in[2];
  const float* whh = (const float*)d_in[3];
  const float* bih = (const float*)d_in[4];
  const float* bhh = (const float*)d_in[5];
  char* ws = (char*)d_ws;
  int* flags = (int*)(ws + OFF_FLAGS);
  float* hpart = (float*)(ws + OFF_HPART);
  u32* hd = (u32*)(ws + OFF_HD);
  float* xn = (float*)(ws + OFF_XNORM);
  float* out = (float*)d_out;

  xnorm_kernel<<<4096, 256, 0, stream>>>(x, xn);
  pregemm_kernel<<<4096, 256, 0, stream>>>(x, wih, bih, bhh, (u16*)d_out);
  hipFuncSetAttribute((const void*)recurrent_kernel,
                      hipFuncAttributeMaxDynamicSharedMemorySize, 156672);
  recurrent_kernel<<<256, 256, 156672, stream>>>(g, whh, xn, hd, hpart, flags, out);
}

// Round 3
// 2873.248 us; speedup vs baseline: 1.1760x; 1.1760x over previous
//
#include <hip/hip_runtime.h>
#include <hip/hip_bf16.h>

typedef unsigned short u16;
typedef unsigned int u32;
typedef unsigned long long u64;
typedef __attribute__((ext_vector_type(8))) short short8;
typedef __attribute__((ext_vector_type(4))) float floatx4;
typedef __attribute__((ext_vector_type(4))) unsigned int u32x4;

#define EPS 0.01f

// ---- workspace layout (bytes) --- total 630784 B ----
#define OFF_FLAGS  (0ull)         // int  [4][64]            1024 B
#define OFF_HPART  (4096ull)      // fp32 [2][4][16][64]     32768 B
#define OFF_HD     (40960ull)     // u32  [2][4][16][1024]   524288 B (lo16=h bf16, hi16=dh bf16)
#define OFF_XNORM  (565248ull)    // fp32 [16384]            65536 B

__device__ __forceinline__ u16 f2b(float v) {
  __hip_bfloat16 b = __float2bfloat16(v);
  return *reinterpret_cast<u16*>(&b);
}
__device__ __forceinline__ float b2f(u16 u) {
  u32 x = ((u32)u) << 16;
  return __uint_as_float(x);
}
__device__ __forceinline__ float halfsel(float w, int hi) {
  u32 u = __float_as_uint(w);
  return b2f((u16)(hi ? (u >> 16) : (u & 0xffffu)));
}
__device__ __forceinline__ float sigm(float x) { return 1.0f / (1.0f + __expf(-x)); }
__device__ __forceinline__ float tanh_(float x) { return 2.0f / (1.0f + __expf(-2.0f * x)) - 1.0f; }

__device__ __forceinline__ u64 ld_sys_u64(const u64* p) {
  return __hip_atomic_load(p, __ATOMIC_RELAXED, __HIP_MEMORY_SCOPE_SYSTEM);
}

// prex chunk addressing (unchanged): pre-activation for (m = t*64+b,
// col = q*1024 + jt*16 + jj) lives as bf16 inside d_out at fp32 word
// (q>=2 ? 16777216 : 0) + m*1024 + jt*16 + (q&1)*8 + (jj>>1), half = jj&1.

// ---------------- xnorm2[t*64+b] = sum_k x[t,b,k]^2 ----------------
__global__ void xnorm_kernel(const float* __restrict__ x, float* __restrict__ xn) {
  const int wid = threadIdx.x >> 6, lane = threadIdx.x & 63;
  const int row = blockIdx.x * 4 + wid;
  const float4* p = (const float4*)(x + (size_t)row * 1024);
  float s = 0.f;
  #pragma unroll
  for (int i = 0; i < 4; ++i) {
    float4 v = p[lane + i * 64];
    s += v.x * v.x + v.y * v.y + v.z * v.z + v.w * v.w;
  }
  for (int o = 32; o; o >>= 1) s += __shfl_down(s, o);
  if (lane == 0) xn[row] = s;
}

// ------- prex = x @ W_ih^T + (b_ih+b_hh), fp32 in, bf16 chunks into d_out -------
#define LDA 88
__global__ __launch_bounds__(256) void pregemm_kernel(const float* __restrict__ A,
                                                      const float* __restrict__ Bw,
                                                      const float* __restrict__ bih,
                                                      const float* __restrict__ bhh,
                                                      u16* __restrict__ O) {
  __shared__ u16 Al[128 * LDA];
  __shared__ u16 Bl[128 * LDA];
  const int tid = threadIdx.x, lane = tid & 63, wid = tid >> 6;
  const int bm = blockIdx.x & 127, bn = blockIdx.x >> 7;
  const size_t m0 = (size_t)bm * 128, n0 = (size_t)bn * 128;
  const int wrow = (wid & 1) * 64, wcol = (wid >> 1) * 64;
  const int lrow = lane & 15, lko = (lane >> 4) * 8;
  floatx4 acc[4][4];
  #pragma unroll
  for (int i = 0; i < 4; ++i)
    #pragma unroll
    for (int j = 0; j < 4; ++j) acc[i][j] = (floatx4)(0.0f);

  for (int k0 = 0; k0 < 1024; k0 += 64) {
    __syncthreads();
    #pragma unroll
    for (int i = 0; i < 8; ++i) {
      int cid = tid + i * 256;
      int row = cid >> 4;
      int kc = cid & 15;
      float4 va = *(const float4*)&A[(m0 + row) * 1024 + k0 + kc * 4];
      ushort4 oa;
      oa.x = f2b(va.x); oa.y = f2b(va.y); oa.z = f2b(va.z); oa.w = f2b(va.w);
      *(ushort4*)&Al[row * LDA + kc * 4] = oa;
      float4 vb = *(const float4*)&Bw[(n0 + row) * 1024 + k0 + kc * 4];
      ushort4 ob;
      ob.x = f2b(vb.x); ob.y = f2b(vb.y); ob.z = f2b(vb.z); ob.w = f2b(vb.w);
      *(ushort4*)&Bl[row * LDA + kc * 4] = ob;
    }
    __syncthreads();
    #pragma unroll
    for (int ks = 0; ks < 2; ++ks) {
      short8 af[4], bf[4];
      #pragma unroll
      for (int i = 0; i < 4; ++i)
        af[i] = *(const short8*)&Al[(wrow + i * 16 + lrow) * LDA + ks * 32 + lko];
      #pragma unroll
      for (int j = 0; j < 4; ++j)
        bf[j] = *(const short8*)&Bl[(wcol + j * 16 + lrow) * LDA + ks * 32 + lko];
      #pragma unroll
      for (int i = 0; i < 4; ++i)
        #pragma unroll
        for (int j = 0; j < 4; ++j)
          acc[i][j] = __builtin_amdgcn_mfma_f32_16x16x32_bf16(af[i], bf[j], acc[i][j], 0, 0, 0);
    }
  }
  #pragma unroll
  for (int j = 0; j < 4; ++j) {
    const size_t col = n0 + wcol + j * 16 + lrow;
    const float bv = bih[col] + bhh[col];
    const size_t q = col >> 10;
    const size_t jt = (col & 1023) >> 4;
    const size_t jj = col & 15;
    const size_t cbase = ((q >= 2) ? 33554432ull : 0ull) + jt * 32 + (q & 1) * 16 + jj;
    #pragma unroll
    for (int i = 0; i < 4; ++i) {
      const size_t rowb = m0 + wrow + i * 16 + (lane >> 4) * 4;
      #pragma unroll
      for (int r = 0; r < 4; ++r) O[cbase + (rowb + r) * 2048] = f2b(acc[i][j][r] + bv);
    }
  }
}

// ---------------- persistent recurrent kernel v5 ----------------
// v3/v4 post-mortem: VGPR stuck at 84 both times -> the A-load batch never
// materialized (compiler sank the atomic loads / shuffled the 34 tiny asm
// statements). v5 forces it with ONE mega-asm block: 16 global_load_dwordx4
// (A-row bytes are contiguous: 2 quads per ks) with 16 early-clobber "=&v"
// outputs + one per-lane base address and 13-bit immediate offsets. A single
// asm statement cannot be split or partially spilled -> RA must keep all 64
// dest VGPRs live -> one pipelined system-scope latency instead of eight.
// Also: out[] HBM stores moved AFTER the end-of-step barrier + flag store
// (not consumed cross-WG; removes HBM store drain from the flag path).
__global__ __launch_bounds__(256, 1) void recurrent_kernel(
    const float* __restrict__ gin, const float* __restrict__ whh,
    const float* __restrict__ xnorm2, u32* hd, float* hpart, int* flags, float* out) {
  extern __shared__ char smem[];
  u16* Wlds = (u16*)smem;                   // [64][1032]  132096 B
  float* rbuf = (float*)(smem + 132096);    // [2][4][4][3][64] fp32 = 24576 B

  const int tid = threadIdx.x, lane = tid & 63, wid = tid >> 6;
  const int grp = blockIdx.x & 3, jt = blockIdx.x >> 2;
  const int lrow = lane & 15, hv = lane >> 4, lko = hv * 8;
  const int j = jt * 16 + lrow;     // this lane's output column
  const int bloc = hv * 4 + wid;    // this lane's local batch row (0..15)
  const int pj = wid * 16 + lrow;   // producer jt this lane polls (wave's K quarter)

  // W_hh slice: LDS row q*16+jj <- global row q*1024 + jt*16 + jj (fp32 -> bf16)
  #pragma unroll
  for (int it = 0; it < 64; ++it) {
    int cid = tid + it * 256;
    int rowl = cid >> 8;
    int kc = cid & 255;
    int q = rowl >> 4, jj = rowl & 15;
    size_t grow = (size_t)q * 1024 + (size_t)jt * 16 + jj;
    float4 v = *(const float4*)&whh[grow * 1024 + kc * 4];
    ushort4 o;
    o.x = f2b(v.x); o.y = f2b(v.y); o.z = f2b(v.z); o.w = f2b(v.w);
    *(ushort4*)&Wlds[rowl * 1032 + kc * 4] = o;
  }
  __syncthreads();

  float cr = 0.f, dcr = 0.f;

  for (int t = 0; t < 256; ++t) {
    const int p = t & 1, p2 = p ^ 1;
    const size_t m = (size_t)t * 64 + grp * 16 + bloc;

    // ---- prefetch (producer-independent data) BEFORE the poll ----
    float gv[4];
    #pragma unroll
    for (int q = 0; q < 4; ++q) gv[q] = EPS * gin[m * 4096 + (size_t)q * 1024 + j];
    const size_t fb = m * 1024 + (size_t)jt * 16 + (lrow >> 1);
    float pw0 = out[fb];
    float pw1 = out[fb + 8];
    float pw2 = out[16777216ull + fb];
    float pw3 = out[16777216ull + fb + 8];
    float xnv = xnorm2[m];
    asm volatile("" ::: "memory");  // pin prefetch issue before the poll

    floatx4 acc[2][4];
    #pragma unroll
    for (int m2 = 0; m2 < 2; ++m2)
      #pragma unroll
      for (int q = 0; q < 4; ++q) acc[m2][q] = (floatx4)(0.0f);

    u32x4 Q[16];
    u64 q0v = 0, q1v = 0;  // hpart quads (issued with the batch, consumed post-barrier)

    if (t > 0) {
      // ---- per-wave poll: only this wave's 16 producers (own jt exempt) ----
      for (int it = 0; it < 4000000; ++it) {
        int v = __hip_atomic_load(&flags[grp * 64 + pj], __ATOMIC_RELAXED,
                                  __HIP_MEMORY_SCOPE_SYSTEM);
        if (pj == jt) v = 0x7fffffff;
        if (__all(v >= t)) break;
        __builtin_amdgcn_s_sleep(1);
      }
      asm volatile("" ::: "memory");

      // ---- the batch: 16 x dwordx4 (=256B/lane, the wave's full A K-quarter)
      //      in ONE asm statement; unsplittable -> truly in flight together ----
      const u32* ap = hd + ((size_t)(p * 4 + grp)) * 16384 + (size_t)lrow * 1024 +
                      (size_t)(wid * 256 + lko);
      asm volatile(
          "global_load_dwordx4 %0, %16, off sc0 sc1\n\t"
          "global_load_dwordx4 %1, %16, off offset:16 sc0 sc1\n\t"
          "global_load_dwordx4 %2, %16, off offset:128 sc0 sc1\n\t"
          "global_load_dwordx4 %3, %16, off offset:144 sc0 sc1\n\t"
          "global_load_dwordx4 %4, %16, off offset:256 sc0 sc1\n\t"
          "global_load_dwordx4 %5, %16, off offset:272 sc0 sc1\n\t"
          "global_load_dwordx4 %6, %16, off offset:384 sc0 sc1\n\t"
          "global_load_dwordx4 %7, %16, off offset:400 sc0 sc1\n\t"
          "global_load_dwordx4 %8, %16, off offset:512 sc0 sc1\n\t"
          "global_load_dwordx4 %9, %16, off offset:528 sc0 sc1\n\t"
          "global_load_dwordx4 %10, %16, off offset:640 sc0 sc1\n\t"
          "global_load_dwordx4 %11, %16, off offset:656 sc0 sc1\n\t"
          "global_load_dwordx4 %12, %16, off offset:768 sc0 sc1\n\t"
          "global_load_dwordx4 %13, %16, off offset:784 sc0 sc1\n\t"
          "global_load_dwordx4 %14, %16, off offset:896 sc0 sc1\n\t"
          "global_load_dwordx4 %15, %16, off offset:912 sc0 sc1"
          : "=&v"(Q[0]), "=&v"(Q[1]), "=&v"(Q[2]), "=&v"(Q[3]),
            "=&v"(Q[4]), "=&v"(Q[5]), "=&v"(Q[6]), "=&v"(Q[7]),
            "=&v"(Q[8]), "=&v"(Q[9]), "=&v"(Q[10]), "=&v"(Q[11]),
            "=&v"(Q[12]), "=&v"(Q[13]), "=&v"(Q[14]), "=&v"(Q[15])
          : "v"(ap)
          : "memory");
      // hpart quads join the same drain window
      const u64* hp = (const u64*)(hpart + ((size_t)(p * 4 + grp) * 16 + bloc) * 64 + lrow * 4);
      asm volatile("global_load_dwordx2 %0, %2, off sc0 sc1\n\t"
                   "global_load_dwordx2 %1, %2, off offset:8 sc0 sc1"
                   : "=&v"(q0v), "=&v"(q1v) : "v"(hp) : "memory");
      asm volatile("s_waitcnt vmcnt(0)" ::: "memory");
      __builtin_amdgcn_sched_barrier(0);  // rule #18: keep unpack below the wait

      // ---- GEMM: wave wid owns K quarter [wid*256, wid*256+256) ----
      #pragma unroll
      for (int ks = 0; ks < 8; ++ks) {
        u32 w[8] = {Q[2 * ks][0], Q[2 * ks][1], Q[2 * ks][2], Q[2 * ks][3],
                    Q[2 * ks + 1][0], Q[2 * ks + 1][1], Q[2 * ks + 1][2], Q[2 * ks + 1][3]};
        short8 a0, a1;
        #pragma unroll
        for (int i = 0; i < 4; ++i) {
          u32 lo = w[2 * i];
          u32 hi2 = w[2 * i + 1];
          // a0 word i = lo16(w[2i]) | lo16(w[2i+1])<<16 ; a1 = hi16 halves
          ((u32*)&a0)[i] = __builtin_amdgcn_perm(hi2, lo, 0x05040100u);
          ((u32*)&a1)[i] = __builtin_amdgcn_perm(hi2, lo, 0x07060302u);
        }
        const int k0 = wid * 256 + ks * 32;
        #pragma unroll
        for (int q = 0; q < 4; ++q) {
          short8 bq = *(const short8*)&Wlds[(q * 16 + lrow) * 1032 + k0 + lko];
          acc[0][q] = __builtin_amdgcn_mfma_f32_16x16x32_bf16(a0, bq, acc[0][q], 0, 0, 0);
          acc[1][q] = __builtin_amdgcn_mfma_f32_16x16x32_bf16(a1, bq, acc[1][q], 0, 0, 0);
        }
      }
    }

    // ---- cross-wave K reduction: wave w keeps element r=w, exchanges the rest ----
    float fin[2][4] = {{0.f, 0.f, 0.f, 0.f}, {0.f, 0.f, 0.f, 0.f}};
    float hn = 0.f;
    if (t > 0) {
      // rbuf WAR vs step t-1 reads is covered by the end-of-step barrier
      #pragma unroll
      for (int m2 = 0; m2 < 2; ++m2)
        #pragma unroll
        for (int q = 0; q < 4; ++q)
          #pragma unroll
          for (int s2 = 0; s2 < 3; ++s2) {
            int r = s2 + (s2 >= wid ? 1 : 0);
            rbuf[((((m2 * 4 + q) * 4 + wid) * 3 + s2) << 6) + lane] = acc[m2][q][r];
          }
      __syncthreads();
      #pragma unroll
      for (int m2 = 0; m2 < 2; ++m2)
        #pragma unroll
        for (int q = 0; q < 4; ++q) {
          float sfin = acc[m2][q][wid];
          #pragma unroll
          for (int w2 = 0; w2 < 4; ++w2)
            if (w2 != wid) {
              int slot = wid - (wid > w2 ? 1 : 0);
              sfin += rbuf[((((m2 * 4 + q) * 4 + w2) * 3 + slot) << 6) + lane];
            }
          fin[m2][q] = sfin;
        }
      // ---- |h|^2: data already in q0v/q1v from the batch ----
      float s = __uint_as_float((u32)q0v) + __uint_as_float((u32)(q0v >> 32)) +
                __uint_as_float((u32)q1v) + __uint_as_float((u32)(q1v >> 32));
      s += __shfl_xor(s, 1);
      s += __shfl_xor(s, 2);
      s += __shfl_xor(s, 4);
      s += __shfl_xor(s, 8);
      hn = s;
    }

    // ---- epilogue: one cell (bloc, j) per lane ----
    float h2, dh2;
    {
      const int hi = lrow & 1;
      float pre0 = halfsel(pw0, hi), pre1 = halfsel(pw1, hi);
      float pre2 = halfsel(pw2, hi), pre3 = halfsel(pw3, hi);
      float sum2 = xnv + hn;
      float nrm = sqrtf(sum2 + 2.0f);
      float inv = 1.0f / nrm;
      float s_ = sum2 * inv;
      float pv0 = fin[0][0] + pre0, pv1 = fin[0][1] + pre1;
      float pv2 = fin[0][2] + pre2, pv3 = fin[0][3] + pre3;
      float d0 = gv[0] * (s_ + inv) + gv[1] * inv + fin[1][0];
      float d1 = gv[1] * s_ + (gv[2] + gv[3]) * inv + fin[1][1];
      float d2 = gv[2] * s_ + (gv[0] + gv[1]) * inv + fin[1][2];
      float d3 = gv[3] * s_ + (gv[2] + gv[3]) * inv + fin[1][3];
      float iv = sigm(pv0), fv = sigm(pv1), gg = tanh_(pv2), ov = sigm(pv3);
      float di = iv * (1.f - iv) * d0;
      float df = fv * (1.f - fv) * d1;
      float dgg = (1.f - gg * gg) * d2;
      float dov = ov * (1.f - ov) * d3;
      float c2 = fv * cr + iv * gg;
      float dc2 = df * cr + fv * dcr + di * gg + iv * dgg;
      float tc = tanh_(c2);
      h2 = ov * tc;
      dh2 = dov * tc + ov * (1.f - tc * tc) * dc2;
      cr = c2;
      dcr = dc2;
      u32 packv = (u32)f2b(h2) | ((u32)f2b(dh2) << 16);
      __hip_atomic_store(&hd[((size_t)(p2 * 4 + grp)) * 16384 + (size_t)bloc * 1024 + j],
                         packv, __ATOMIC_RELAXED, __HIP_MEMORY_SCOPE_SYSTEM);
      float v2 = h2 * h2;
      v2 += __shfl_xor(v2, 1);
      v2 += __shfl_xor(v2, 2);
      v2 += __shfl_xor(v2, 4);
      v2 += __shfl_xor(v2, 8);
      if (lrow == 0)
        __hip_atomic_store(&hpart[((size_t)(p2 * 4 + grp) * 16 + bloc) * 64 + jt],
                           v2, __ATOMIC_RELAXED, __HIP_MEMORY_SCOPE_SYSTEM);
    }
    __syncthreads();  // drains vmcnt for ALL waves' hd/hpart stores before flag
    if (tid == 0)
      __hip_atomic_store(&flags[grp * 64 + jt], t + 1, __ATOMIC_RELAXED,
                         __HIP_MEMORY_SCOPE_SYSTEM);
    // out[] stores deferred past the flag: pure output, not consumed cross-WG;
    // disjoint from next step's prex prefetch (higher m rows). Their drain
    // overlaps the next step's poll.
    out[m * 1024 + j] = h2;
    out[16777216ull + m * 1024 + j] = dh2;
  }
}

extern "C" void kernel_launch(void* const* d_in, const int* in_sizes, int n_in,
                              void* d_out, int out_size, void* d_ws, size_t ws_size,
                              hipStream_t stream) {
  const float* x = (const float*)d_in[0];
  const float* g = (const float*)d_in[1];
  const float* wih = (const float*)d_in[2];
  const float* whh = (const float*)d_in[3];
  const float* bih = (const float*)d_in[4];
  const float* bhh = (const float*)d_in[5];
  char* ws = (char*)d_ws;
  int* flags = (int*)(ws + OFF_FLAGS);
  float* hpart = (float*)(ws + OFF_HPART);
  u32* hd = (u32*)(ws + OFF_HD);
  float* xn = (float*)(ws + OFF_XNORM);
  float* out = (float*)d_out;

  xnorm_kernel<<<4096, 256, 0, stream>>>(x, xn);
  pregemm_kernel<<<4096, 256, 0, stream>>>(x, wih, bih, bhh, (u16*)d_out);
  hipFuncSetAttribute((const void*)recurrent_kernel,
                      hipFuncAttributeMaxDynamicSharedMemorySize, 156672);
  recurrent_kernel<<<256, 256, 156672, stream>>>(g, whh, xn, hd, hpart, flags, out);
}

// Round 4
// 2357.380 us; speedup vs baseline: 1.4333x; 1.2188x over previous
//
#include <hip/hip_runtime.h>
#include <hip/hip_bf16.h>

typedef unsigned short u16;
typedef unsigned int u32;
typedef unsigned long long u64;
typedef __attribute__((ext_vector_type(8))) short short8;
typedef __attribute__((ext_vector_type(4))) float floatx4;
typedef __attribute__((ext_vector_type(4))) unsigned int u32x4;

#define EPS 0.01f

// ---- workspace layout (bytes) --- total 630784 B ----
// flags padded to 16B stride: 4 grps x 64 x 16B = 4096 B (fills old slack
// exactly; spreads poll traffic over 64 cache lines instead of 16).
#define OFF_FLAGS  (0ull)         // int  [4][64][4 (pad)]   4096 B
#define OFF_HPART  (4096ull)      // fp32 [2][4][16][64]     32768 B
#define OFF_HD     (40960ull)     // u32  [2][4][16][1024]   524288 B (lo16=h bf16, hi16=dh bf16)
#define OFF_XNORM  (565248ull)    // fp32 [16384]            65536 B

__device__ __forceinline__ u16 f2b(float v) {
  __hip_bfloat16 b = __float2bfloat16(v);
  return *reinterpret_cast<u16*>(&b);
}
__device__ __forceinline__ float b2f(u16 u) {
  u32 x = ((u32)u) << 16;
  return __uint_as_float(x);
}
__device__ __forceinline__ float halfsel(float w, int hi) {
  u32 u = __float_as_uint(w);
  return b2f((u16)(hi ? (u >> 16) : (u & 0xffffu)));
}
__device__ __forceinline__ float sigm(float x) { return 1.0f / (1.0f + __expf(-x)); }
__device__ __forceinline__ float tanh_(float x) { return 2.0f / (1.0f + __expf(-2.0f * x)) - 1.0f; }

// prex chunk addressing (unchanged): pre-activation for (m = t*64+b,
// col = q*1024 + jt*16 + jj) lives as bf16 inside d_out at fp32 word
// (q>=2 ? 16777216 : 0) + m*1024 + jt*16 + (q&1)*8 + (jj>>1), half = jj&1.

// ---------------- xnorm2[t*64+b] = sum_k x[t,b,k]^2 ----------------
__global__ void xnorm_kernel(const float* __restrict__ x, float* __restrict__ xn) {
  const int wid = threadIdx.x >> 6, lane = threadIdx.x & 63;
  const int row = blockIdx.x * 4 + wid;
  const float4* p = (const float4*)(x + (size_t)row * 1024);
  float s = 0.f;
  #pragma unroll
  for (int i = 0; i < 4; ++i) {
    float4 v = p[lane + i * 64];
    s += v.x * v.x + v.y * v.y + v.z * v.z + v.w * v.w;
  }
  for (int o = 32; o; o >>= 1) s += __shfl_down(s, o);
  if (lane == 0) xn[row] = s;
}

// ------- prex = x @ W_ih^T + (b_ih+b_hh), fp32 in, bf16 chunks into d_out -------
#define LDA 88
__global__ __launch_bounds__(256) void pregemm_kernel(const float* __restrict__ A,
                                                      const float* __restrict__ Bw,
                                                      const float* __restrict__ bih,
                                                      const float* __restrict__ bhh,
                                                      u16* __restrict__ O) {
  __shared__ u16 Al[128 * LDA];
  __shared__ u16 Bl[128 * LDA];
  const int tid = threadIdx.x, lane = tid & 63, wid = tid >> 6;
  const int bm = blockIdx.x & 127, bn = blockIdx.x >> 7;
  const size_t m0 = (size_t)bm * 128, n0 = (size_t)bn * 128;
  const int wrow = (wid & 1) * 64, wcol = (wid >> 1) * 64;
  const int lrow = lane & 15, lko = (lane >> 4) * 8;
  floatx4 acc[4][4];
  #pragma unroll
  for (int i = 0; i < 4; ++i)
    #pragma unroll
    for (int j = 0; j < 4; ++j) acc[i][j] = (floatx4)(0.0f);

  for (int k0 = 0; k0 < 1024; k0 += 64) {
    __syncthreads();
    #pragma unroll
    for (int i = 0; i < 8; ++i) {
      int cid = tid + i * 256;
      int row = cid >> 4;
      int kc = cid & 15;
      float4 va = *(const float4*)&A[(m0 + row) * 1024 + k0 + kc * 4];
      ushort4 oa;
      oa.x = f2b(va.x); oa.y = f2b(va.y); oa.z = f2b(va.z); oa.w = f2b(va.w);
      *(ushort4*)&Al[row * LDA + kc * 4] = oa;
      float4 vb = *(const float4*)&Bw[(n0 + row) * 1024 + k0 + kc * 4];
      ushort4 ob;
      ob.x = f2b(vb.x); ob.y = f2b(vb.y); ob.z = f2b(vb.z); ob.w = f2b(vb.w);
      *(ushort4*)&Bl[row * LDA + kc * 4] = ob;
    }
    __syncthreads();
    #pragma unroll
    for (int ks = 0; ks < 2; ++ks) {
      short8 af[4], bf[4];
      #pragma unroll
      for (int i = 0; i < 4; ++i)
        af[i] = *(const short8*)&Al[(wrow + i * 16 + lrow) * LDA + ks * 32 + lko];
      #pragma unroll
      for (int j = 0; j < 4; ++j)
        bf[j] = *(const short8*)&Bl[(wcol + j * 16 + lrow) * LDA + ks * 32 + lko];
      #pragma unroll
      for (int i = 0; i < 4; ++i)
        #pragma unroll
        for (int j = 0; j < 4; ++j)
          acc[i][j] = __builtin_amdgcn_mfma_f32_16x16x32_bf16(af[i], bf[j], acc[i][j], 0, 0, 0);
    }
  }
  #pragma unroll
  for (int j = 0; j < 4; ++j) {
    const size_t col = n0 + wcol + j * 16 + lrow;
    const float bv = bih[col] + bhh[col];
    const size_t q = col >> 10;
    const size_t jt = (col & 1023) >> 4;
    const size_t jj = col & 15;
    const size_t cbase = ((q >= 2) ? 33554432ull : 0ull) + jt * 32 + (q & 1) * 16 + jj;
    #pragma unroll
    for (int i = 0; i < 4; ++i) {
      const size_t rowb = m0 + wrow + i * 16 + (lane >> 4) * 4;
      #pragma unroll
      for (int r = 0; r < 4; ++r) O[cbase + (rowb + r) * 2048] = f2b(acc[i][j][r] + bv);
    }
  }
}

// ---------------- persistent recurrent kernel v6 ----------------
// = round-0 structure EXACTLY (all-wave 64-flag poll, hn before GEMM,
// 3 barriers/step, out[] stores in epilogue), with only two deltas, each
// with isolated positive evidence:
//  (1) mega-asm batched A-loads (v5: proved -2.2k cy/step vs serialized;
//      VGPR 88 = batch-materialized witness) + hpart joins the drain.
//  (2) flags padded to 16B stride: 16k lanes polling 16 mall lines with
//      system-scope loads is a hot-spot; 64 lines cuts per-line pressure 4x.
// The v3 bundle (per-wave poll / deferred hn / dropped barrier / moved
// out-stores) measured +4.5k cy/step across rounds 1-3 -> reverted wholesale.
__global__ __launch_bounds__(256, 1) void recurrent_kernel(
    const float* __restrict__ gin, const float* __restrict__ whh,
    const float* __restrict__ xnorm2, u32* hd, float* hpart, int* flags, float* out) {
  extern __shared__ char smem[];
  u16* Wlds = (u16*)smem;                   // [64][1032]  132096 B
  float* rbuf = (float*)(smem + 132096);    // [2][4][4][3][64] fp32 = 24576 B

  const int tid = threadIdx.x, lane = tid & 63, wid = tid >> 6;
  const int grp = blockIdx.x & 3, jt = blockIdx.x >> 2;
  const int lrow = lane & 15, hv = lane >> 4, lko = hv * 8;
  const int j = jt * 16 + lrow;     // this lane's output column
  const int bloc = hv * 4 + wid;    // this lane's local batch row (0..15)

  // W_hh slice: LDS row q*16+jj <- global row q*1024 + jt*16 + jj (fp32 -> bf16)
  #pragma unroll
  for (int it = 0; it < 64; ++it) {
    int cid = tid + it * 256;
    int rowl = cid >> 8;
    int kc = cid & 255;
    int q = rowl >> 4, jj = rowl & 15;
    size_t grow = (size_t)q * 1024 + (size_t)jt * 16 + jj;
    float4 v = *(const float4*)&whh[grow * 1024 + kc * 4];
    ushort4 o;
    o.x = f2b(v.x); o.y = f2b(v.y); o.z = f2b(v.z); o.w = f2b(v.w);
    *(ushort4*)&Wlds[rowl * 1032 + kc * 4] = o;
  }
  __syncthreads();

  float cr = 0.f, dcr = 0.f;

  for (int t = 0; t < 256; ++t) {
    const int p = t & 1, p2 = p ^ 1;
    const size_t m = (size_t)t * 64 + grp * 16 + bloc;

    // ---- prefetch (producer-independent data) BEFORE the poll ----
    float gv[4];
    #pragma unroll
    for (int q = 0; q < 4; ++q) gv[q] = EPS * gin[m * 4096 + (size_t)q * 1024 + j];
    const size_t fb = m * 1024 + (size_t)jt * 16 + (lrow >> 1);
    float pw0 = out[fb];
    float pw1 = out[fb + 8];
    float pw2 = out[16777216ull + fb];
    float pw3 = out[16777216ull + fb + 8];
    float xnv = xnorm2[m];
    asm volatile("" ::: "memory");  // pin prefetch issue before the poll

    floatx4 acc[2][4];
    #pragma unroll
    for (int m2 = 0; m2 < 2; ++m2)
      #pragma unroll
      for (int q = 0; q < 4; ++q) acc[m2][q] = (floatx4)(0.0f);

    float hn = 0.f;
    u32x4 Q[16];

    if (t > 0) {
      // ---- all waves poll all 64 producer flags of this grp (own jt exempt);
      //      flags at 16B stride -> 64 distinct cache lines ----
      for (int it = 0; it < 4000000; ++it) {
        int v = __hip_atomic_load(&flags[(grp * 64 + lane) * 4], __ATOMIC_RELAXED,
                                  __HIP_MEMORY_SCOPE_SYSTEM);
        if (lane == jt) v = 0x7fffffff;
        if (__all(v >= t)) break;
        __builtin_amdgcn_s_sleep(1);
      }
      asm volatile("" ::: "memory");

      // ---- mega-asm batch: 16 x dwordx4 = the wave's full A K-quarter in ONE
      //      unsplittable statement -> all in flight together (v5-verified) ----
      const u32* ap = hd + ((size_t)(p * 4 + grp)) * 16384 + (size_t)lrow * 1024 +
                      (size_t)(wid * 256 + lko);
      asm volatile(
          "global_load_dwordx4 %0, %16, off sc0 sc1\n\t"
          "global_load_dwordx4 %1, %16, off offset:16 sc0 sc1\n\t"
          "global_load_dwordx4 %2, %16, off offset:128 sc0 sc1\n\t"
          "global_load_dwordx4 %3, %16, off offset:144 sc0 sc1\n\t"
          "global_load_dwordx4 %4, %16, off offset:256 sc0 sc1\n\t"
          "global_load_dwordx4 %5, %16, off offset:272 sc0 sc1\n\t"
          "global_load_dwordx4 %6, %16, off offset:384 sc0 sc1\n\t"
          "global_load_dwordx4 %7, %16, off offset:400 sc0 sc1\n\t"
          "global_load_dwordx4 %8, %16, off offset:512 sc0 sc1\n\t"
          "global_load_dwordx4 %9, %16, off offset:528 sc0 sc1\n\t"
          "global_load_dwordx4 %10, %16, off offset:640 sc0 sc1\n\t"
          "global_load_dwordx4 %11, %16, off offset:656 sc0 sc1\n\t"
          "global_load_dwordx4 %12, %16, off offset:768 sc0 sc1\n\t"
          "global_load_dwordx4 %13, %16, off offset:784 sc0 sc1\n\t"
          "global_load_dwordx4 %14, %16, off offset:896 sc0 sc1\n\t"
          "global_load_dwordx4 %15, %16, off offset:912 sc0 sc1"
          : "=&v"(Q[0]), "=&v"(Q[1]), "=&v"(Q[2]), "=&v"(Q[3]),
            "=&v"(Q[4]), "=&v"(Q[5]), "=&v"(Q[6]), "=&v"(Q[7]),
            "=&v"(Q[8]), "=&v"(Q[9]), "=&v"(Q[10]), "=&v"(Q[11]),
            "=&v"(Q[12]), "=&v"(Q[13]), "=&v"(Q[14]), "=&v"(Q[15])
          : "v"(ap)
          : "memory");
      // hpart quads join the same drain window
      u64 q0v, q1v;
      const u64* hp = (const u64*)(hpart + ((size_t)(p * 4 + grp) * 16 + bloc) * 64 + lrow * 4);
      asm volatile("global_load_dwordx2 %0, %2, off sc0 sc1\n\t"
                   "global_load_dwordx2 %1, %2, off offset:8 sc0 sc1"
                   : "=&v"(q0v), "=&v"(q1v) : "v"(hp) : "memory");
      asm volatile("s_waitcnt vmcnt(0)" ::: "memory");
      __builtin_amdgcn_sched_barrier(0);  // rule #18: keep consumers below the wait

      // ---- |h|^2 reduce (round-0 position: before GEMM) ----
      {
        float s = __uint_as_float((u32)q0v) + __uint_as_float((u32)(q0v >> 32)) +
                  __uint_as_float((u32)q1v) + __uint_as_float((u32)(q1v >> 32));
        s += __shfl_xor(s, 1);
        s += __shfl_xor(s, 2);
        s += __shfl_xor(s, 4);
        s += __shfl_xor(s, 8);
        hn = s;
      }

      // ---- GEMM: wave wid owns K quarter [wid*256, wid*256+256) ----
      #pragma unroll
      for (int ks = 0; ks < 8; ++ks) {
        u32 w[8] = {Q[2 * ks][0], Q[2 * ks][1], Q[2 * ks][2], Q[2 * ks][3],
                    Q[2 * ks + 1][0], Q[2 * ks + 1][1], Q[2 * ks + 1][2], Q[2 * ks + 1][3]};
        short8 a0, a1;
        #pragma unroll
        for (int i = 0; i < 4; ++i) {
          u32 lo = w[2 * i];
          u32 hi2 = w[2 * i + 1];
          // a0 word i = lo16(w[2i]) | lo16(w[2i+1])<<16 ; a1 = hi16 halves
          ((u32*)&a0)[i] = __builtin_amdgcn_perm(hi2, lo, 0x05040100u);
          ((u32*)&a1)[i] = __builtin_amdgcn_perm(hi2, lo, 0x07060302u);
        }
        const int k0 = wid * 256 + ks * 32;
        #pragma unroll
        for (int q = 0; q < 4; ++q) {
          short8 bq = *(const short8*)&Wlds[(q * 16 + lrow) * 1032 + k0 + lko];
          acc[0][q] = __builtin_amdgcn_mfma_f32_16x16x32_bf16(a0, bq, acc[0][q], 0, 0, 0);
          acc[1][q] = __builtin_amdgcn_mfma_f32_16x16x32_bf16(a1, bq, acc[1][q], 0, 0, 0);
        }
      }
    }

    // ---- cross-wave K reduction: wave w keeps element r=w, exchanges the rest
    //      (round-0 three-barrier structure kept verbatim) ----
    float fin[2][4] = {{0.f, 0.f, 0.f, 0.f}, {0.f, 0.f, 0.f, 0.f}};
    if (t > 0) {
      __syncthreads();  // all GEMMs done
      #pragma unroll
      for (int m2 = 0; m2 < 2; ++m2)
        #pragma unroll
        for (int q = 0; q < 4; ++q)
          #pragma unroll
          for (int s2 = 0; s2 < 3; ++s2) {
            int r = s2 + (s2 >= wid ? 1 : 0);
            rbuf[((((m2 * 4 + q) * 4 + wid) * 3 + s2) << 6) + lane] = acc[m2][q][r];
          }
      __syncthreads();
      #pragma unroll
      for (int m2 = 0; m2 < 2; ++m2)
        #pragma unroll
        for (int q = 0; q < 4; ++q) {
          float sfin = acc[m2][q][wid];
          #pragma unroll
          for (int w2 = 0; w2 < 4; ++w2)
            if (w2 != wid) {
              int slot = wid - (wid > w2 ? 1 : 0);
              sfin += rbuf[((((m2 * 4 + q) * 4 + w2) * 3 + slot) << 6) + lane];
            }
          fin[m2][q] = sfin;
        }
    }

    // ---- epilogue: one cell (bloc, j) per lane ----
    {
      const int hi = lrow & 1;
      float pre0 = halfsel(pw0, hi), pre1 = halfsel(pw1, hi);
      float pre2 = halfsel(pw2, hi), pre3 = halfsel(pw3, hi);
      float sum2 = xnv + hn;
      float nrm = sqrtf(sum2 + 2.0f);
      float inv = 1.0f / nrm;
      float s_ = sum2 * inv;
      float pv0 = fin[0][0] + pre0, pv1 = fin[0][1] + pre1;
      float pv2 = fin[0][2] + pre2, pv3 = fin[0][3] + pre3;
      float d0 = gv[0] * (s_ + inv) + gv[1] * inv + fin[1][0];
      float d1 = gv[1] * s_ + (gv[2] + gv[3]) * inv + fin[1][1];
      float d2 = gv[2] * s_ + (gv[0] + gv[1]) * inv + fin[1][2];
      float d3 = gv[3] * s_ + (gv[2] + gv[3]) * inv + fin[1][3];
      float iv = sigm(pv0), fv = sigm(pv1), gg = tanh_(pv2), ov = sigm(pv3);
      float di = iv * (1.f - iv) * d0;
      float df = fv * (1.f - fv) * d1;
      float dgg = (1.f - gg * gg) * d2;
      float dov = ov * (1.f - ov) * d3;
      float c2 = fv * cr + iv * gg;
      float dc2 = df * cr + fv * dcr + di * gg + iv * dgg;
      float tc = tanh_(c2);
      float h2 = ov * tc;
      float dh2 = dov * tc + ov * (1.f - tc * tc) * dc2;
      cr = c2;
      dcr = dc2;
      out[m * 1024 + j] = h2;
      out[16777216ull + m * 1024 + j] = dh2;
      u32 packv = (u32)f2b(h2) | ((u32)f2b(dh2) << 16);
      __hip_atomic_store(&hd[((size_t)(p2 * 4 + grp)) * 16384 + (size_t)bloc * 1024 + j],
                         packv, __ATOMIC_RELAXED, __HIP_MEMORY_SCOPE_SYSTEM);
      float v2 = h2 * h2;
      v2 += __shfl_xor(v2, 1);
      v2 += __shfl_xor(v2, 2);
      v2 += __shfl_xor(v2, 4);
      v2 += __shfl_xor(v2, 8);
      if (lrow == 0)
        __hip_atomic_store(&hpart[((size_t)(p2 * 4 + grp) * 16 + bloc) * 64 + jt],
                           v2, __ATOMIC_RELAXED, __HIP_MEMORY_SCOPE_SYSTEM);
    }
    __syncthreads();  // drains vmcnt for ALL waves' state stores before flag
    if (tid == 0)
      __hip_atomic_store(&flags[(grp * 64 + jt) * 4], t + 1, __ATOMIC_RELAXED,
                         __HIP_MEMORY_SCOPE_SYSTEM);
  }
}

extern "C" void kernel_launch(void* const* d_in, const int* in_sizes, int n_in,
                              void* d_out, int out_size, void* d_ws, size_t ws_size,
                              hipStream_t stream) {
  const float* x = (const float*)d_in[0];
  const float* g = (const float*)d_in[1];
  const float* wih = (const float*)d_in[2];
  const float* whh = (const float*)d_in[3];
  const float* bih = (const float*)d_in[4];
  const float* bhh = (const float*)d_in[5];
  char* ws = (char*)d_ws;
  int* flags = (int*)(ws + OFF_FLAGS);
  float* hpart = (float*)(ws + OFF_HPART);
  u32* hd = (u32*)(ws + OFF_HD);
  float* xn = (float*)(ws + OFF_XNORM);
  float* out = (float*)d_out;

  xnorm_kernel<<<4096, 256, 0, stream>>>(x, xn);
  pregemm_kernel<<<4096, 256, 0, stream>>>(x, wih, bih, bhh, (u16*)d_out);
  hipFuncSetAttribute((const void*)recurrent_kernel,
                      hipFuncAttributeMaxDynamicSharedMemorySize, 156672);
  recurrent_kernel<<<256, 256, 156672, stream>>>(g, whh, xn, hd, hpart, flags, out);
}